// Round 8
// baseline (85.848 us; speedup 1.0000x reference)
//
#include <hip/hip_runtime.h>
#include <math.h>

// ChamferDistance: B=4, N=M=8192, 3-D fp32 points.
// out[0] = mean_i sqrt(min_j d2)*w  +  mean_j sqrt(min_i d2)
//
// MFMA formulation (R6+): d2 = qsq + (rsq - 2 q.r) as a K=5 dot on
// v_mfma_f32_32x32x16_f16 (32 refs x 32 queries = 1024 pairs/inst):
//   A (refs)    = (-2rx,-2ry,-2rz, rsq_hi, rsq_lo, 0,0,0) f16, lanes 0-31
//   B (queries) = (  qx,  qy,  qz,   1,      1,    0,0,0) f16, lanes 0-31
// lanes 32-63 (k=8..15) zero. D: col=lane&31=query; 16 regs x lane-half =
// 32 refs -> per-lane min3 fold + one shfl_xor(32). absmax 0.0 verified.
//
// R8: (1) single-D sequencing — fold d0 before issuing the B1 MFMA so only
// one f32x16 accumulator is live (~65 VGPR demand), comfortably under the
// __launch_bounds__(256,6) 85-VGPR cap -> no scratch spills (R7 suspect:
// both-MFMAs-grouped schedule needed ~110 regs > 85 cap -> K-loop spills).
// (2) single-block reduce writes out[0] directly (no memset(out), no atomics).

#define EPS 1e-8f

typedef _Float16 f16x8 __attribute__((ext_vector_type(8)));
typedef float    f32x16 __attribute__((ext_vector_type(16)));

constexpr int B_    = 4;
constexpr int N_    = 8192;          // points per batch (N == M)
constexpr int TPB   = 256;           // 4 waves
constexpr int QPW   = 64;            // queries per wave (2 tiles of 32)
constexpr int QPB   = 4 * QPW;       // 256 queries per block
constexpr int RCH   = 8;             // ref chunks (grid.y)
constexpr int CHUNK = N_ / RCH;      // 1024 refs staged per block (16 KB)

// grid: (N/QPB=32, RCH=8, 2*B=8) = 2048 blocks -> 8 blocks/CU by grid,
// 6 waves/SIMD by VGPR cap.
__global__ __launch_bounds__(TPB, 6)
void nn_mfma_kernel(const float* __restrict__ src, const float* __restrict__ tgt,
                    unsigned int* __restrict__ minA, unsigned int* __restrict__ minB)
{
    __shared__ f16x8 sref[CHUNK + 64];   // +64: zero slot & safe prefetch pad

    const int zb  = blockIdx.z;
    const int dir = zb >> 2;            // 0: src queries tgt, 1: tgt queries src
    const int b   = zb & 3;
    const float* Rraw = (dir ? src : tgt) + ((size_t)b * N_ + (size_t)blockIdx.y * CHUNK) * 3;
    const float* Qraw = (dir ? tgt : src) + (size_t)b * N_ * 3;
    unsigned int* omin = (dir ? minB : minA) + (size_t)b * N_;

    const int tid = threadIdx.x;
    const _Float16 h0 = (_Float16)0.f;
    const _Float16 h1 = (_Float16)1.f;

    // stage + quantize refs inline: (-2x,-2y,-2z, rsq_hi, rsq_lo, 0,0,0)
    for (int k = tid; k < CHUNK; k += TPB) {
        const float* rp = Rraw + (size_t)k * 3;
        _Float16 hx = (_Float16)rp[0], hy = (_Float16)rp[1], hz = (_Float16)rp[2];
        float fx = (float)hx, fy = (float)hy, fz = (float)hz;
        float rsq = fx * fx + fy * fy + fz * fz;
        _Float16 rh = (_Float16)rsq;
        _Float16 rl = (_Float16)(rsq - (float)rh);
        f16x8 a = {(_Float16)(-2.f * fx), (_Float16)(-2.f * fy),
                   (_Float16)(-2.f * fz), rh, rl, h0, h0, h0};
        sref[k] = a;
    }
    if (tid < 64) {
        f16x8 z = {h0, h0, h0, h0, h0, h0, h0, h0};
        sref[CHUNK + tid] = z;
    }

    const int lane = tid & 63;
    const int wv   = tid >> 6;
    const int l31  = lane & 31;
    const int half = lane >> 5;          // 0: carries data (k=0..7), 1: zeros
    const int qb   = blockIdx.x * QPB + wv * QPW;

    // B fragments quantized inline; lanes 32-63 stay zero (k=8..15)
    f16x8 B0 = {h0, h0, h0, h0, h0, h0, h0, h0};
    f16x8 B1 = B0;
    float qs0 = 0.f, qs1 = 0.f;
    if (half == 0) {
        const float* q0 = Qraw + (size_t)(qb + l31) * 3;
        const float* q1 = Qraw + (size_t)(qb + 32 + l31) * 3;
        _Float16 ax = (_Float16)q0[0], ay = (_Float16)q0[1], az = (_Float16)q0[2];
        _Float16 bx = (_Float16)q1[0], by = (_Float16)q1[1], bz = (_Float16)q1[2];
        float fax = (float)ax, fay = (float)ay, faz = (float)az;
        float fbx = (float)bx, fby = (float)by, fbz = (float)bz;
        B0 = f16x8{ax, ay, az, h1, h1, h0, h0, h0};
        B1 = f16x8{bx, by, bz, h1, h1, h0, h0, h0};
        qs0 = fax * fax + fay * fay + faz * faz;
        qs1 = fbx * fbx + fby * fby + fbz * fbz;
    }
    __syncthreads();

    f32x16 zc;
#pragma unroll
    for (int i = 0; i < 16; ++i) zc[i] = 0.f;

    // K-loop: prefetch next A; SINGLE D live at a time (fold d0 before the
    // B1 MFMA issues). 4 independent min chains. 1 ds_read_b128 + 2 MFMA +
    // 16 v_min3 per step.
    int idx = (half == 0) ? l31 : CHUNK;
    const int step = (half == 0) ? 32 : 0;
    float mn0a = 3.0e38f, mn0b = 3.0e38f, mn1a = 3.0e38f, mn1b = 3.0e38f;

    f16x8 a = sref[idx];
    idx += step;
    for (int s = 0; s < CHUNK / 32; ++s) {
        f16x8 an = sref[idx];            // tail prefetch lands in pad (unused)
        idx += step;
        {
            f32x16 d0 = __builtin_amdgcn_mfma_f32_32x32x16_f16(a, B0, zc, 0, 0, 0);
#pragma unroll
            for (int r = 0; r < 8; r += 2)
                mn0a = fminf(fminf(d0[r], d0[r + 1]), mn0a);   // v_min3_f32
#pragma unroll
            for (int r = 8; r < 16; r += 2)
                mn0b = fminf(fminf(d0[r], d0[r + 1]), mn0b);
        }
        {
            f32x16 d1 = __builtin_amdgcn_mfma_f32_32x32x16_f16(a, B1, zc, 0, 0, 0);
#pragma unroll
            for (int r = 0; r < 8; r += 2)
                mn1a = fminf(fminf(d1[r], d1[r + 1]), mn1a);
#pragma unroll
            for (int r = 8; r < 16; r += 2)
                mn1b = fminf(fminf(d1[r], d1[r + 1]), mn1b);
        }
        a = an;
    }

    float mn0 = fminf(mn0a, mn0b);
    float mn1 = fminf(mn1a, mn1b);
    // rows split across lane halves: one xor-32 merge covers all 32 refs/tile
    mn0 = fminf(mn0, __shfl_xor(mn0, 32));
    mn1 = fminf(mn1, __shfl_xor(mn1, 32));
    if (half == 0) {
        atomicMin(&omin[qb + l31],      __float_as_uint(fmaxf(mn0 + qs0, 0.f)));
        atomicMin(&omin[qb + 32 + l31], __float_as_uint(fmaxf(mn1 + qs1, 0.f)));
    }
}

// single-block reduce: 1024 threads grid-stride both min arrays, wave/LDS
// tree, thread 0 writes out[0] directly (no pre-zero, no atomics).
constexpr int RTPB = 1024;
__global__ __launch_bounds__(RTPB)
void reduce_kernel(const unsigned int* __restrict__ minA,
                   const unsigned int* __restrict__ minB,
                   const float* __restrict__ w,
                   float* __restrict__ out)
{
    const int BN = B_ * N_;
    const float invBN = 1.0f / (float)BN;

    float sum = 0.0f;
    for (int t = threadIdx.x; t < BN; t += RTPB) {
        sum += sqrtf(__uint_as_float(minA[t]) + EPS) * w[t];
        sum += sqrtf(__uint_as_float(minB[t]) + EPS);
    }
    sum *= invBN;

    __shared__ float ss[RTPB / 64];
    int lane = threadIdx.x & 63;
    int wid  = threadIdx.x >> 6;
#pragma unroll
    for (int off = 32; off > 0; off >>= 1) sum += __shfl_down(sum, off);
    if (lane == 0) ss[wid] = sum;
    __syncthreads();
    if (threadIdx.x == 0) {
        float s = 0.0f;
#pragma unroll
        for (int i = 0; i < RTPB / 64; ++i) s += ss[i];
        out[0] = s;
    }
}

extern "C" void kernel_launch(void* const* d_in, const int* in_sizes, int n_in,
                              void* d_out, int out_size, void* d_ws, size_t ws_size,
                              hipStream_t stream)
{
    const float* src = (const float*)d_in[0];   // (B, N, 3)
    const float* tgt = (const float*)d_in[1];   // (B, M, 3)
    const float* w   = (const float*)d_in[2];   // (B, N)
    float* out = (float*)d_out;

    const size_t BN = (size_t)B_ * N_;
    unsigned int* minA = (unsigned int*)d_ws;   // BN uint
    unsigned int* minB = minA + BN;             // BN uint

    // 0x7F7F7F7F = 3.39e38f: valid "infinity" for uint-bit atomicMin on floats >= 0
    hipMemsetAsync(minA, 0x7F, 2 * BN * sizeof(unsigned int), stream);

    dim3 grid(N_ / QPB, RCH, 2 * B_);   // 32 x 8 x 8 = 2048 blocks
    nn_mfma_kernel<<<grid, TPB, 0, stream>>>(src, tgt, minA, minB);

    reduce_kernel<<<1, RTPB, 0, stream>>>(minA, minB, w, out);
}

// Round 9
// 77.091 us; speedup vs baseline: 1.1136x; 1.1136x over previous
//
#include <hip/hip_runtime.h>
#include <math.h>

// ChamferDistance: B=4, N=M=8192, 3-D fp32 points.
// out[0] = mean_i sqrt(min_j d2)*w  +  mean_j sqrt(min_i d2)
//
// MFMA formulation (R6+): d2 = qsq + (rsq - 2 q.r) as a K=5 dot on
// v_mfma_f32_32x32x16_f16 (32 refs x 32 queries = 1024 pairs/inst):
//   A (refs)    = (-2rx,-2ry,-2rz, rsq_hi, rsq_lo, 0,0,0) f16, lanes 0-31
//   B (queries) = (  qx,  qy,  qz,   1,      1,    0,0,0) f16, lanes 0-31
// lanes 32-63 (k=8..15) zero. D: col=lane&31=query; 16 regs x lane-half =
// 32 refs -> per-lane min3 fold + one shfl_xor(32). absmax 0.0 verified.
//
// R9: R8 proved the loop is MFMA-LATENCY-exposed (serializing 2->1 in-flight
// MFMAs cost +9us; lower reg pressure didn't help). So: 4 query tiles per
// wave (QPW=128) -> 4 independent MFMAs per ds_read step, interleaved with
// folds (<=3 D tiles live, ~80 VGPR under the 85 cap of lb(256,6)).
// RCH=16 keeps grid at 2048 blocks -> 6 waves/SIMD resident.
// In-flight MFMAs: 6 waves x 4 = 24 (R7: 12). Epilogue reverted to R7 form.

#define EPS 1e-8f

typedef _Float16 f16x8 __attribute__((ext_vector_type(8)));
typedef float    f32x16 __attribute__((ext_vector_type(16)));

constexpr int B_    = 4;
constexpr int N_    = 8192;          // points per batch (N == M)
constexpr int TPB   = 256;           // 4 waves
constexpr int QPW   = 128;           // queries per wave (4 tiles of 32)
constexpr int QPB   = 4 * QPW;       // 512 queries per block
constexpr int RCH   = 16;            // ref chunks (grid.y)
constexpr int CHUNK = N_ / RCH;      // 512 refs staged per block (8 KB)
constexpr int RB    = 64;            // reduce blocks

// grid: (N/QPB=16, RCH=16, 2*B=8) = 2048 blocks -> 8 blocks/CU by grid,
// 6 waves/SIMD by VGPR cap.
__global__ __launch_bounds__(TPB, 6)
void nn_mfma_kernel(const float* __restrict__ src, const float* __restrict__ tgt,
                    unsigned int* __restrict__ minA, unsigned int* __restrict__ minB)
{
    __shared__ f16x8 sref[CHUNK + 64];   // +64: zero slot & safe prefetch pad

    const int zb  = blockIdx.z;
    const int dir = zb >> 2;            // 0: src queries tgt, 1: tgt queries src
    const int b   = zb & 3;
    const float* Rraw = (dir ? src : tgt) + ((size_t)b * N_ + (size_t)blockIdx.y * CHUNK) * 3;
    const float* Qraw = (dir ? tgt : src) + (size_t)b * N_ * 3;
    unsigned int* omin = (dir ? minB : minA) + (size_t)b * N_;

    const int tid = threadIdx.x;
    const _Float16 h0 = (_Float16)0.f;
    const _Float16 h1 = (_Float16)1.f;

    // stage + quantize refs inline: (-2x,-2y,-2z, rsq_hi, rsq_lo, 0,0,0)
    for (int k = tid; k < CHUNK; k += TPB) {
        const float* rp = Rraw + (size_t)k * 3;
        _Float16 hx = (_Float16)rp[0], hy = (_Float16)rp[1], hz = (_Float16)rp[2];
        float fx = (float)hx, fy = (float)hy, fz = (float)hz;
        float rsq = fx * fx + fy * fy + fz * fz;
        _Float16 rh = (_Float16)rsq;
        _Float16 rl = (_Float16)(rsq - (float)rh);
        f16x8 a = {(_Float16)(-2.f * fx), (_Float16)(-2.f * fy),
                   (_Float16)(-2.f * fz), rh, rl, h0, h0, h0};
        sref[k] = a;
    }
    if (tid < 64) {
        f16x8 z = {h0, h0, h0, h0, h0, h0, h0, h0};
        sref[CHUNK + tid] = z;
    }

    const int lane = tid & 63;
    const int wv   = tid >> 6;
    const int l31  = lane & 31;
    const int half = lane >> 5;          // 0: carries data (k=0..7), 1: zeros
    const int qb   = blockIdx.x * QPB + wv * QPW;

    // 4 B fragments quantized inline; lanes 32-63 stay zero (k=8..15)
    f16x8 Bq[4];
    float qs[4];
#pragma unroll
    for (int t = 0; t < 4; ++t) {
        Bq[t] = f16x8{h0, h0, h0, h0, h0, h0, h0, h0};
        qs[t] = 0.f;
    }
    if (half == 0) {
#pragma unroll
        for (int t = 0; t < 4; ++t) {
            const float* q = Qraw + (size_t)(qb + t * 32 + l31) * 3;
            _Float16 ax = (_Float16)q[0], ay = (_Float16)q[1], az = (_Float16)q[2];
            float fx = (float)ax, fy = (float)ay, fz = (float)az;
            Bq[t] = f16x8{ax, ay, az, h1, h1, h0, h0, h0};
            qs[t] = fx * fx + fy * fy + fz * fz;
        }
    }
    __syncthreads();

    const f32x16 zc = {};   // expect inline-0 fold for MFMA src2

    // K-loop: 1 ds_read_b128 feeds 4 independent MFMAs; folds interleaved so
    // >=2 MFMAs stay in flight while <=3 D tiles are live.
    int idx = (half == 0) ? l31 : CHUNK;
    const int step = (half == 0) ? 32 : 0;
    float mna[4] = {3.0e38f, 3.0e38f, 3.0e38f, 3.0e38f};
    float mnb[4] = {3.0e38f, 3.0e38f, 3.0e38f, 3.0e38f};

    f16x8 a = sref[idx];
    idx += step;
    for (int s = 0; s < CHUNK / 32; ++s) {
        f16x8 an = sref[idx];            // tail prefetch lands in pad (unused)
        idx += step;
        f32x16 d0 = __builtin_amdgcn_mfma_f32_32x32x16_f16(a, Bq[0], zc, 0, 0, 0);
        f32x16 d1 = __builtin_amdgcn_mfma_f32_32x32x16_f16(a, Bq[1], zc, 0, 0, 0);
#pragma unroll
        for (int r = 0; r < 8; r += 2)
            mna[0] = fminf(fminf(d0[r], d0[r + 1]), mna[0]);   // v_min3_f32
#pragma unroll
        for (int r = 8; r < 16; r += 2)
            mnb[0] = fminf(fminf(d0[r], d0[r + 1]), mnb[0]);
        f32x16 d2 = __builtin_amdgcn_mfma_f32_32x32x16_f16(a, Bq[2], zc, 0, 0, 0);
#pragma unroll
        for (int r = 0; r < 8; r += 2)
            mna[1] = fminf(fminf(d1[r], d1[r + 1]), mna[1]);
#pragma unroll
        for (int r = 8; r < 16; r += 2)
            mnb[1] = fminf(fminf(d1[r], d1[r + 1]), mnb[1]);
        f32x16 d3 = __builtin_amdgcn_mfma_f32_32x32x16_f16(a, Bq[3], zc, 0, 0, 0);
#pragma unroll
        for (int r = 0; r < 8; r += 2)
            mna[2] = fminf(fminf(d2[r], d2[r + 1]), mna[2]);
#pragma unroll
        for (int r = 8; r < 16; r += 2)
            mnb[2] = fminf(fminf(d2[r], d2[r + 1]), mnb[2]);
#pragma unroll
        for (int r = 0; r < 8; r += 2)
            mna[3] = fminf(fminf(d3[r], d3[r + 1]), mna[3]);
#pragma unroll
        for (int r = 8; r < 16; r += 2)
            mnb[3] = fminf(fminf(d3[r], d3[r + 1]), mnb[3]);
        a = an;
    }

#pragma unroll
    for (int t = 0; t < 4; ++t) {
        float mn = fminf(mna[t], mnb[t]);
        // rows split across lane halves: one xor-32 merge covers all 32 refs
        mn = fminf(mn, __shfl_xor(mn, 32));
        if (half == 0)
            atomicMin(&omin[qb + t * 32 + l31],
                      __float_as_uint(fmaxf(mn + qs[t], 0.f)));
    }
}

// reduce: partial sums -> wave/block reduce -> atomicAdd into out[0]
__global__ __launch_bounds__(TPB)
void reduce_kernel(const unsigned int* __restrict__ minA,
                   const unsigned int* __restrict__ minB,
                   const float* __restrict__ w,
                   float* __restrict__ out)
{
    const int BN = B_ * N_;
    const float invBN = 1.0f / (float)BN;

    float sum = 0.0f;
    for (int t = blockIdx.x * TPB + threadIdx.x; t < BN; t += RB * TPB) {
        sum += sqrtf(__uint_as_float(minA[t]) + EPS) * w[t];
        sum += sqrtf(__uint_as_float(minB[t]) + EPS);
    }
    sum *= invBN;

    __shared__ float ss[TPB / 64];
    int lane = threadIdx.x & 63;
    int wid  = threadIdx.x >> 6;
#pragma unroll
    for (int off = 32; off > 0; off >>= 1) sum += __shfl_down(sum, off);
    if (lane == 0) ss[wid] = sum;
    __syncthreads();
    if (threadIdx.x == 0) {
        float s = 0.0f;
#pragma unroll
        for (int i = 0; i < TPB / 64; ++i) s += ss[i];
        atomicAdd(out, s);
    }
}

extern "C" void kernel_launch(void* const* d_in, const int* in_sizes, int n_in,
                              void* d_out, int out_size, void* d_ws, size_t ws_size,
                              hipStream_t stream)
{
    const float* src = (const float*)d_in[0];   // (B, N, 3)
    const float* tgt = (const float*)d_in[1];   // (B, M, 3)
    const float* w   = (const float*)d_in[2];   // (B, N)
    float* out = (float*)d_out;

    const size_t BN = (size_t)B_ * N_;
    unsigned int* minA = (unsigned int*)d_ws;   // BN uint
    unsigned int* minB = minA + BN;             // BN uint

    // 0x7F7F7F7F = 3.39e38f: valid "infinity" for uint-bit atomicMin on floats >= 0
    hipMemsetAsync(minA, 0x7F, 2 * BN * sizeof(unsigned int), stream);
    hipMemsetAsync(out, 0, sizeof(float), stream);

    dim3 grid(N_ / QPB, RCH, 2 * B_);   // 16 x 16 x 8 = 2048 blocks
    nn_mfma_kernel<<<grid, TPB, 0, stream>>>(src, tgt, minA, minB);

    reduce_kernel<<<RB, TPB, 0, stream>>>(minA, minB, w, out);
}

// Round 10
// 76.043 us; speedup vs baseline: 1.1289x; 1.0138x over previous
//
#include <hip/hip_runtime.h>
#include <math.h>

// ChamferDistance: B=4, N=M=8192, 3-D fp32 points.
// out[0] = mean_i sqrt(min_j d2)*w  +  mean_j sqrt(min_i d2)
//
// MFMA formulation (R6+): d2 = qsq + (rsq - 2 q.r) as a K=5 dot on
// v_mfma_f32_32x32x16_f16 (32 refs x 32 queries = 1024 pairs/inst):
//   A (refs)    = (-2rx,-2ry,-2rz, rsq_hi, rsq_lo, 0,0,0) f16, lanes 0-31
//   B (queries) = (  qx,  qy,  qz,   1,      1,    0,0,0) f16, lanes 0-31
// lanes 32-63 (k=8..15) zero. D: col=lane&31=query; 16 regs x lane-half =
// 32 refs -> per-lane min3 fold + one shfl_xor(32). absmax 0.0 verified.
//
// R10: dispatch surgery. R7==R9 showed the K-loop shape isn't binding; the
// R6->R7 delta (-6.9us/dispatch removed) says launch+gap overhead ~3-5us
// each. So: (1) per-chunk partial-min STORES (every slot written -> no
// memset, no atomicMin); (2) nn block(0,0,0) zeroes out[0] (kills the
// second memset); (3) reduce min-folds the 8 partials per query. 4->2
// dispatches. K-loop is R7's proven shape, unchanged.

#define EPS 1e-8f

typedef _Float16 f16x8 __attribute__((ext_vector_type(8)));
typedef float    f32x16 __attribute__((ext_vector_type(16)));

constexpr int B_    = 4;
constexpr int N_    = 8192;          // points per batch (N == M)
constexpr int TPB   = 256;           // 4 waves
constexpr int QPW   = 64;            // queries per wave (2 tiles of 32)
constexpr int QPB   = 4 * QPW;       // 256 queries per block
constexpr int RCH   = 8;             // ref chunks (grid.y)
constexpr int CHUNK = N_ / RCH;      // 1024 refs staged per block (16 KB)
constexpr int RB    = 64;            // reduce blocks

// grid: (N/QPB=32, RCH=8, 2*B=8) = 2048 blocks.
// part layout: part[(zb*RCH + c)*N + q]  (zb = dir*4+b), 2 MB total.
__global__ __launch_bounds__(TPB, 6)
void nn_mfma_kernel(const float* __restrict__ src, const float* __restrict__ tgt,
                    float* __restrict__ part, float* __restrict__ out)
{
    __shared__ f16x8 sref[CHUNK + 64];   // +64: zero slot & safe prefetch pad

    if (blockIdx.x == 0 && blockIdx.y == 0 && blockIdx.z == 0 && threadIdx.x == 0)
        out[0] = 0.f;                    // reduce (next dispatch) atomicAdds

    const int zb  = blockIdx.z;
    const int dir = zb >> 2;            // 0: src queries tgt, 1: tgt queries src
    const int b   = zb & 3;
    const float* Rraw = (dir ? src : tgt) + ((size_t)b * N_ + (size_t)blockIdx.y * CHUNK) * 3;
    const float* Qraw = (dir ? tgt : src) + (size_t)b * N_ * 3;
    float* opart = part + ((size_t)zb * RCH + blockIdx.y) * N_;

    const int tid = threadIdx.x;
    const _Float16 h0 = (_Float16)0.f;
    const _Float16 h1 = (_Float16)1.f;

    // stage + quantize refs inline: (-2x,-2y,-2z, rsq_hi, rsq_lo, 0,0,0)
    for (int k = tid; k < CHUNK; k += TPB) {
        const float* rp = Rraw + (size_t)k * 3;
        _Float16 hx = (_Float16)rp[0], hy = (_Float16)rp[1], hz = (_Float16)rp[2];
        float fx = (float)hx, fy = (float)hy, fz = (float)hz;
        float rsq = fx * fx + fy * fy + fz * fz;
        _Float16 rh = (_Float16)rsq;
        _Float16 rl = (_Float16)(rsq - (float)rh);
        f16x8 a = {(_Float16)(-2.f * fx), (_Float16)(-2.f * fy),
                   (_Float16)(-2.f * fz), rh, rl, h0, h0, h0};
        sref[k] = a;
    }
    if (tid < 64) {
        f16x8 z = {h0, h0, h0, h0, h0, h0, h0, h0};
        sref[CHUNK + tid] = z;
    }

    const int lane = tid & 63;
    const int wv   = tid >> 6;
    const int l31  = lane & 31;
    const int half = lane >> 5;          // 0: carries data (k=0..7), 1: zeros
    const int qb   = blockIdx.x * QPB + wv * QPW;

    // B fragments quantized inline; lanes 32-63 stay zero (k=8..15)
    f16x8 B0 = {h0, h0, h0, h0, h0, h0, h0, h0};
    f16x8 B1 = B0;
    float qs0 = 0.f, qs1 = 0.f;
    if (half == 0) {
        const float* q0 = Qraw + (size_t)(qb + l31) * 3;
        const float* q1 = Qraw + (size_t)(qb + 32 + l31) * 3;
        _Float16 ax = (_Float16)q0[0], ay = (_Float16)q0[1], az = (_Float16)q0[2];
        _Float16 bx = (_Float16)q1[0], by = (_Float16)q1[1], bz = (_Float16)q1[2];
        float fax = (float)ax, fay = (float)ay, faz = (float)az;
        float fbx = (float)bx, fby = (float)by, fbz = (float)bz;
        B0 = f16x8{ax, ay, az, h1, h1, h0, h0, h0};
        B1 = f16x8{bx, by, bz, h1, h1, h0, h0, h0};
        qs0 = fax * fax + fay * fay + faz * faz;
        qs1 = fbx * fbx + fby * fby + fbz * fbz;
    }
    __syncthreads();

    const f32x16 zc = {};

    // K-loop (R7 shape): prefetch next A; issue both MFMAs, fold d0 then d1;
    // 4 independent min chains.
    int idx = (half == 0) ? l31 : CHUNK;
    const int step = (half == 0) ? 32 : 0;
    float mn0a = 3.0e38f, mn0b = 3.0e38f, mn1a = 3.0e38f, mn1b = 3.0e38f;

    f16x8 a = sref[idx];
    idx += step;
    for (int s = 0; s < CHUNK / 32; ++s) {
        f16x8 an = sref[idx];            // tail prefetch lands in pad (unused)
        idx += step;
        f32x16 d0 = __builtin_amdgcn_mfma_f32_32x32x16_f16(a, B0, zc, 0, 0, 0);
        f32x16 d1 = __builtin_amdgcn_mfma_f32_32x32x16_f16(a, B1, zc, 0, 0, 0);
#pragma unroll
        for (int r = 0; r < 8; r += 2)
            mn0a = fminf(fminf(d0[r], d0[r + 1]), mn0a);   // v_min3_f32
#pragma unroll
        for (int r = 8; r < 16; r += 2)
            mn0b = fminf(fminf(d0[r], d0[r + 1]), mn0b);
#pragma unroll
        for (int r = 0; r < 8; r += 2)
            mn1a = fminf(fminf(d1[r], d1[r + 1]), mn1a);
#pragma unroll
        for (int r = 8; r < 16; r += 2)
            mn1b = fminf(fminf(d1[r], d1[r + 1]), mn1b);
        a = an;
    }

    float mn0 = fminf(mn0a, mn0b);
    float mn1 = fminf(mn1a, mn1b);
    // rows split across lane halves: one xor-32 merge covers all 32 refs/tile
    mn0 = fminf(mn0, __shfl_xor(mn0, 32));
    mn1 = fminf(mn1, __shfl_xor(mn1, 32));
    if (half == 0) {
        opart[qb + l31]      = fmaxf(mn0 + qs0, 0.f);   // plain store, no init
        opart[qb + 32 + l31] = fmaxf(mn1 + qs1, 0.f);
    }
}

// reduce: per query min over RCH partials -> sqrt -> weight -> sum ->
// atomicAdd into out[0] (zeroed by nn). 2 MB of partials, L2-resident.
__global__ __launch_bounds__(TPB)
void reduce_kernel(const float* __restrict__ part,
                   const float* __restrict__ w,
                   float* __restrict__ out)
{
    const int Q = 2 * B_ * N_;               // 65536 queries
    const float invBN = 1.0f / (float)(B_ * N_);

    float sum = 0.0f;
    for (int t = blockIdx.x * TPB + threadIdx.x; t < Q; t += RB * TPB) {
        const int zb = t >> 13;              // t / N_
        const int qn = t & (N_ - 1);
        const float* p = part + ((size_t)zb * RCH) * N_ + qn;
        float m = p[0];
#pragma unroll
        for (int c = 1; c < RCH; ++c) m = fminf(m, p[(size_t)c * N_]);
        float d = sqrtf(m + EPS);
        sum += (zb < 4) ? d * w[(size_t)zb * N_ + qn] : d;
    }
    sum *= invBN;

    __shared__ float ss[TPB / 64];
    int lane = threadIdx.x & 63;
    int wid  = threadIdx.x >> 6;
#pragma unroll
    for (int off = 32; off > 0; off >>= 1) sum += __shfl_down(sum, off);
    if (lane == 0) ss[wid] = sum;
    __syncthreads();
    if (threadIdx.x == 0) {
        float s = 0.0f;
#pragma unroll
        for (int i = 0; i < TPB / 64; ++i) s += ss[i];
        atomicAdd(out, s);
    }
}

extern "C" void kernel_launch(void* const* d_in, const int* in_sizes, int n_in,
                              void* d_out, int out_size, void* d_ws, size_t ws_size,
                              hipStream_t stream)
{
    const float* src = (const float*)d_in[0];   // (B, N, 3)
    const float* tgt = (const float*)d_in[1];   // (B, M, 3)
    const float* w   = (const float*)d_in[2];   // (B, N)
    float* out = (float*)d_out;

    float* part = (float*)d_ws;   // [2*B][RCH][N] = 2 MB, fully overwritten

    dim3 grid(N_ / QPB, RCH, 2 * B_);   // 32 x 8 x 8 = 2048 blocks
    nn_mfma_kernel<<<grid, TPB, 0, stream>>>(src, tgt, part, out);

    reduce_kernel<<<RB, TPB, 0, stream>>>(part, w, out);
}